// Round 5
// baseline (329.656 us; speedup 1.0000x reference)
//
#include <hip/hip_runtime.h>

// sample_pdf (NeRF hierarchical sampling), fp32.
// bins: [N, 64] sorted edges; weights: [N, 63]; u: [N, 128] -> out [N, 128].
//
// R1: LDS-pipe bound. R2: DPP scan + 3 reg levels (325 us).
// R3: bpermute gathers + flat level-A + rcp. VALU 57->41%, dur flat.
// R4: 2 rays/wave ILP: 107 us. R5: persistent SW pipeline: REGRESSED (126).
// R6: asm keep-alive: no-op (VGPR stayed 16) -> PROVED loads were already
//     overlapped (VMEM addr regs free at issue; only dests tracked). Real
//     sink: wave lifetime ~12.5K cyc = 4 serialized sample chains x TWO
//     dependent LDS rounds each (b128 window ~140cy -> bpermute ~140cy).
// R7 (this): (a) stage bins in LDS beside cdf; ONE read round per sample
//     (cdf window + bins window + [pos+8] pair), then pure-VALU cndmask
//     chains extract lo/chi/blo/bhi from the sorted window. 2 dep rounds -> 1,
//     all 16 bpermutes gone. (b) 4 rays/wave: 8 independent 1-round chains,
//     12 global loads in flight, half the waves.

constexpr int NBINS = 64;
constexpr int NW = NBINS - 1;
constexpr int NIMP = 128;
constexpr int WAVES_PER_BLOCK = 4;
constexpr int RAYS_PER_WAVE = 4;
constexpr int RAYS_PER_BLOCK = WAVES_PER_BLOCK * RAYS_PER_WAVE;  // 16
constexpr int ROW = 2 * NBINS;  // per-ray LDS row: [0..63]=cdf, [64..127]=bins

template <int Ctrl, int Rm>
__device__ __forceinline__ float dppterm(float x) {
    // update_dpp(old=0,...): lanes with invalid source (bound_ctrl) or masked-off
    // rows (row_mask) produce 0, so "x += dppterm(x)" is the identity there.
    return __int_as_float(__builtin_amdgcn_update_dpp(
        0, __float_as_int(x), Ctrl, Rm, 0xF, true));
}

__device__ __forceinline__ float rdlane(float x, int lane) {
    return __int_as_float(__builtin_amdgcn_readlane(__float_as_int(x), lane));
}

// wave64 inclusive scan, pure VALU (DPP), no DS ops
__device__ __forceinline__ float wave_incl_scan(float x) {
    x += dppterm<0x111, 0xF>(x);  // row_shr:1
    x += dppterm<0x112, 0xF>(x);  // row_shr:2
    x += dppterm<0x114, 0xF>(x);  // row_shr:4
    x += dppterm<0x118, 0xF>(x);  // row_shr:8  -> per-16 row scans
    x += dppterm<0x142, 0xA>(x);  // row_bcast:15 -> rows 1,3 get row 0/2 totals
    x += dppterm<0x143, 0xC>(x);  // row_bcast:31 -> lanes 32..63 get total(0..31)
    return x;
}

struct Pivots { float c8, c16, c24, c32, c40, c48, c56; };

__device__ __forceinline__ Pivots make_pivots(float cdfv) {
    Pivots p;
    p.c8  = rdlane(cdfv, 8);
    p.c16 = rdlane(cdfv, 16);
    p.c24 = rdlane(cdfv, 24);
    p.c32 = rdlane(cdfv, 32);
    p.c40 = rdlane(cdfv, 40);
    p.c48 = rdlane(cdfv, 48);
    p.c56 = rdlane(cdfv, 56);
    return p;
}

// One sample: level-A on SGPR pivots -> ONE parallel LDS round (5 reads) ->
// cndmask-chain extraction (sorted window) -> interpolate. Zero bpermutes.
__device__ __forceinline__ float sample_mux(float uv, const float* row,
                                            const Pivots& P)
{
    // level A: which 8-aligned group (pivots sorted => flags monotone => sum)
    const int grp = (int)(P.c8 < uv) + (int)(P.c16 < uv) + (int)(P.c24 < uv) +
                    (int)(P.c32 < uv) + (int)(P.c40 < uv) + (int)(P.c48 < uv) +
                    (int)(P.c56 < uv);
    const int pos = grp << 3;  // 32B-aligned

    // ONE dependent LDS round: cdf window, bins window, +8 pair.
    // All 5 reads independent; compiler clusters them under one lgkm wait.
    const float4 w0 = *(const float4*)(row + pos);
    const float4 w1 = *(const float4*)(row + pos + 4);
    const float4 b0 = *(const float4*)(row + NBINS + pos);
    const float4 b1 = *(const float4*)(row + NBINS + pos + 4);
    const float w8 = row[pos + 8];           // ds_read2_b32 candidates
    const float b8 = row[NBINS + pos + 8];   // (grp=7: garbage, never selected)

    // lower = pos + cnt, cnt = #window-cdf < uv. Instead of materializing the
    // index, select lo=cdf[lower], chi=cdf[lower+1], blo/bhi directly with
    // 7 shared compares driving 4 cndmask chains (window is sorted).
    // cdf[63]=1.0 exact -> at grp=7, w1.w=1.0 >= uv -> c7 false -> w8/b8 unused.
    const bool c1 = w0.y < uv, c2 = w0.z < uv, c3 = w0.w < uv, c4 = w1.x < uv,
               c5 = w1.y < uv, c6 = w1.z < uv, c7 = w1.w < uv;
    float lo = w0.x, chi = w0.y, blo = b0.x, bhi = b0.y;
    if (c1) { lo = w0.y; chi = w0.z; blo = b0.y; bhi = b0.z; }
    if (c2) { lo = w0.z; chi = w0.w; blo = b0.z; bhi = b0.w; }
    if (c3) { lo = w0.w; chi = w1.x; blo = b0.w; bhi = b1.x; }
    if (c4) { lo = w1.x; chi = w1.y; blo = b1.x; bhi = b1.y; }
    if (c5) { lo = w1.y; chi = w1.z; blo = b1.y; bhi = b1.z; }
    if (c6) { lo = w1.z; chi = w1.w; blo = b1.z; bhi = b1.w; }
    if (c7) { lo = w1.w; chi = w8;   blo = b1.w; bhi = b8;   }

    // uv==0: all flags false -> lo=cdf[0]=0, blo=bins[0], t=0 -> bins[0]. Matches
    // reference (idx=0 -> lower=upper=0 -> sample=bins[0]). uv in [0,1) always.
    float denom = chi - lo;
    denom = (denom < 1e-5f) ? 1.0f : denom;
    const float t = (uv - lo) * __builtin_amdgcn_rcpf(denom);
    return __builtin_fmaf(t, bhi - blo, blo);
}

__global__ __launch_bounds__(256) void sample_pdf_kernel(
    const float* __restrict__ bins,
    const float* __restrict__ weights,
    const float* __restrict__ u,
    float* __restrict__ out,
    int n_rays)
{
    // +8 floats pad: grp=7's [pos+8] read on the last bins row stays in-bounds
    __shared__ alignas(16) float s[WAVES_PER_BLOCK * RAYS_PER_WAVE * ROW + 8];

    const int wave = threadIdx.x >> 6;
    const int lane = threadIdx.x & 63;
    const int base = blockIdx.x * RAYS_PER_BLOCK + wave * RAYS_PER_WAVE;

    uint32_t r[RAYS_PER_WAVE];
    #pragma unroll
    for (int i = 0; i < RAYS_PER_WAVE; ++i)
        r[i] = (uint32_t)min(base + i, n_rays - 1);  // tail: benign dup work

    // ---- all 12 global loads issued up front (addr regs free at issue) ----
    float bv[RAYS_PER_WAVE], wr[RAYS_PER_WAVE];
    float2 uu[RAYS_PER_WAVE];
    #pragma unroll
    for (int i = 0; i < RAYS_PER_WAVE; ++i) {
        bv[i] = bins[r[i] * NBINS + lane];
        wr[i] = 0.0f;
        if (lane < NW) wr[i] = weights[r[i] * NW + lane];  // exec-masked, no math
        uu[i] = ((const float2*)u)[r[i] * (NIMP / 2) + lane];
    }
    asm volatile("" :: "v"(bv[0]), "v"(bv[1]), "v"(bv[2]), "v"(bv[3]),
                       "v"(wr[0]), "v"(wr[1]), "v"(wr[2]), "v"(wr[3]),
                       "v"(uu[0].x), "v"(uu[0].y), "v"(uu[1].x), "v"(uu[1].y),
                       "v"(uu[2].x), "v"(uu[2].y), "v"(uu[3].x), "v"(uu[3].y));

    // ---- 4 independent DPP scans -> exclusive normalized cdfs; stage LDS ----
    float cdfv[RAYS_PER_WAVE];
    #pragma unroll
    for (int i = 0; i < RAYS_PER_WAVE; ++i) {
        const float w = (lane < NW) ? (wr[i] + 1e-5f) : 0.0f;
        const float S = wave_incl_scan(w);
        float c = (S - w) * __builtin_amdgcn_rcpf(rdlane(S, 63));
        if (lane == NBINS - 1) c = 1.0f;  // exact top: bounds cnt<=6 at grp=7
        cdfv[i] = c;
        float* row = s + (wave * RAYS_PER_WAVE + i) * ROW;
        // wave-private rows; same-wave write->read ordering via lgkmcnt, no barrier
        row[lane] = c;            // ds_write2_b32 candidates (offsets 0 / 64 dw)
        row[NBINS + lane] = bv[i];
    }

    Pivots P[RAYS_PER_WAVE];
    #pragma unroll
    for (int i = 0; i < RAYS_PER_WAVE; ++i) P[i] = make_pivots(cdfv[i]);

    // ---- 8 independent 1-round sample chains ----
    #pragma unroll
    for (int i = 0; i < RAYS_PER_WAVE; ++i) {
        const float* row = s + (wave * RAYS_PER_WAVE + i) * ROW;
        float2 res;
        res.x = sample_mux(uu[i].x, row, P[i]);
        res.y = sample_mux(uu[i].y, row, P[i]);
        ((float2*)out)[r[i] * (NIMP / 2) + lane] = res;
    }
}

extern "C" void kernel_launch(void* const* d_in, const int* in_sizes, int n_in,
                              void* d_out, int out_size, void* d_ws, size_t ws_size,
                              hipStream_t stream) {
    const float* bins    = (const float*)d_in[0];
    const float* weights = (const float*)d_in[1];
    const float* u       = (const float*)d_in[2];
    float* out = (float*)d_out;

    const int n_rays = in_sizes[0] / NBINS;
    const int grid = (n_rays + RAYS_PER_BLOCK - 1) / RAYS_PER_BLOCK;
    sample_pdf_kernel<<<grid, 256, 0, stream>>>(bins, weights, u, out, n_rays);
}

// Round 6
// 310.749 us; speedup vs baseline: 1.0608x; 1.0608x over previous
//
#include <hip/hip_runtime.h>

// sample_pdf (NeRF hierarchical sampling), fp32.
// bins: [N, 64] sorted edges; weights: [N, 63]; u: [N, 128] -> out [N, 128].
//
// R1: LDS-pipe bound. R2: DPP scan + 3 reg levels (325 us).
// R3: bpermute gathers + flat level-A + rcp. VALU 57->41%, dur flat.
// R4: 2 rays/wave ILP: 107 us (best). R5: persistent pipeline: REGR (126).
// R6: asm keep-alive: no-op -> loads were already overlapped; one global round.
// R7: bins-in-LDS mux + 4 rays/wave: REGR (134). Conflicts 11.5M->29.4M
//     (bins windows + [pos+8] scalar reads), VALU 50%. Reverted.
// R8 (this): R4 per-wave shape, two structural fixes for the residual
//     latency bind (back-computed residency ~2.5-3 waves/SIMD, lifetime ~5K):
//     (a) 1024-thread blocks: 16 waves/WG, 2 WG/CU hits the 2048-thread cap
//         -> rules out workgroup-slot-limited residency. LDS 8KB/block.
//     (b) phase-batched samples: issue ALL 8 window b128s (one lgkm wait),
//         then all cnts, then ALL 16 bpermutes (one wait), then finals.
//         8 dependent LDS rounds/wave -> 2. asm markers pin the phases;
//         __launch_bounds__(1024,8) caps VGPR at 64 (8 waves/SIMD legal).

constexpr int NBINS = 64;
constexpr int NW = NBINS - 1;
constexpr int NIMP = 128;
constexpr int WAVES_PER_BLOCK = 16;   // 1024 threads
constexpr int RAYS_PER_WAVE = 2;
constexpr int RAYS_PER_BLOCK = WAVES_PER_BLOCK * RAYS_PER_WAVE;  // 32

template <int Ctrl, int Rm>
__device__ __forceinline__ float dppterm(float x) {
    // update_dpp(old=0,...): lanes with invalid source (bound_ctrl) or masked-off
    // rows (row_mask) produce 0, so "x += dppterm(x)" is the identity there.
    return __int_as_float(__builtin_amdgcn_update_dpp(
        0, __float_as_int(x), Ctrl, Rm, 0xF, true));
}

__device__ __forceinline__ float rdlane(float x, int lane) {
    return __int_as_float(__builtin_amdgcn_readlane(__float_as_int(x), lane));
}

// pull: result = src@lane[idx] (full wave64 crossbar on register values)
__device__ __forceinline__ float bperm_f(float x, int lane_idx) {
    return __int_as_float(
        __builtin_amdgcn_ds_bpermute(lane_idx << 2, __float_as_int(x)));
}

// wave64 inclusive scan, pure VALU (DPP), no DS ops
__device__ __forceinline__ float wave_incl_scan(float x) {
    x += dppterm<0x111, 0xF>(x);  // row_shr:1
    x += dppterm<0x112, 0xF>(x);  // row_shr:2
    x += dppterm<0x114, 0xF>(x);  // row_shr:4
    x += dppterm<0x118, 0xF>(x);  // row_shr:8  -> per-16 row scans
    x += dppterm<0x142, 0xA>(x);  // row_bcast:15 -> rows 1,3 get row 0/2 totals
    x += dppterm<0x143, 0xC>(x);  // row_bcast:31 -> lanes 32..63 get total(0..31)
    return x;
}

struct Pivots { float c8, c16, c24, c32, c40, c48, c56; };

__device__ __forceinline__ Pivots make_pivots(float cdfv) {
    Pivots p;
    p.c8  = rdlane(cdfv, 8);
    p.c16 = rdlane(cdfv, 16);
    p.c24 = rdlane(cdfv, 24);
    p.c32 = rdlane(cdfv, 32);
    p.c40 = rdlane(cdfv, 40);
    p.c48 = rdlane(cdfv, 48);
    p.c56 = rdlane(cdfv, 56);
    return p;
}

__device__ __forceinline__ int level_a(float uv, const Pivots& P) {
    // pivots sorted => flags monotone => grp = sum; pos = grp*8 (32B-aligned)
    return ((int)(P.c8 < uv) + (int)(P.c16 < uv) + (int)(P.c24 < uv) +
            (int)(P.c32 < uv) + (int)(P.c40 < uv) + (int)(P.c48 < uv) +
            (int)(P.c56 < uv)) << 3;
}

__global__ __launch_bounds__(1024, 8) void sample_pdf_kernel(
    const float* __restrict__ bins,
    const float* __restrict__ weights,
    const float* __restrict__ u,
    float* __restrict__ out,
    int n_rays)
{
    __shared__ alignas(16) float s_cdf[WAVES_PER_BLOCK][RAYS_PER_WAVE][NBINS];

    const int wave = threadIdx.x >> 6;
    const int lane = threadIdx.x & 63;
    const int base = blockIdx.x * RAYS_PER_BLOCK + wave * RAYS_PER_WAVE;
    // tail: clamped rays recompute ray n-1; identical values, benign dup writes
    const uint32_t rA = (uint32_t)min(base,     n_rays - 1);
    const uint32_t rB = (uint32_t)min(base + 1, n_rays - 1);

    // ---- 6 global loads; R6 proved these overlap with one vmcnt round ----
    const float bvA = bins[rA * NBINS + lane];
    const float bvB = bins[rB * NBINS + lane];
    float wrA = 0.0f, wrB = 0.0f;
    if (lane < NW) {
        wrA = weights[rA * NW + lane];
        wrB = weights[rB * NW + lane];
    }
    const float2 uuA = ((const float2*)u)[rA * (NIMP / 2) + lane];
    const float2 uuB = ((const float2*)u)[rB * (NIMP / 2) + lane];

    // ---- two independent DPP scans -> exclusive normalized cdfs ----
    const float wA = (lane < NW) ? (wrA + 1e-5f) : 0.0f;
    const float wB = (lane < NW) ? (wrB + 1e-5f) : 0.0f;
    const float SA = wave_incl_scan(wA);
    const float SB = wave_incl_scan(wB);
    float cdfvA = (SA - wA) * __builtin_amdgcn_rcpf(rdlane(SA, 63));
    float cdfvB = (SB - wB) * __builtin_amdgcn_rcpf(rdlane(SB, 63));
    if (lane == NBINS - 1) { cdfvA = 1.0f; cdfvB = 1.0f; }  // exact top

    // wave-private LDS rows; same-wave write->read order via compiler lgkmcnt
    s_cdf[wave][0][lane] = cdfvA;
    s_cdf[wave][1][lane] = cdfvB;

    const Pivots PA = make_pivots(cdfvA);
    const Pivots PB = make_pivots(cdfvB);

    const float* cA = s_cdf[wave][0];
    const float* cB = s_cdf[wave][1];

    // sample i: {uuA.x, uuA.y, uuB.x, uuB.y}; i<2 -> ray A, else ray B.
    const float uv0 = uuA.x, uv1 = uuA.y, uv2 = uuB.x, uv3 = uuB.y;

    // ---- phase 1: all level-A searches (pure VALU on SGPR pivots) ----
    const int pos0 = level_a(uv0, PA);
    const int pos1 = level_a(uv1, PA);
    const int pos2 = level_a(uv2, PB);
    const int pos3 = level_a(uv3, PB);

    // ---- phase 2: ALL 8 window reads issued back-to-back, ONE lgkm round ----
    const float4 w00 = *(const float4*)(cA + pos0);
    const float4 w01 = *(const float4*)(cA + pos0 + 4);
    const float4 w10 = *(const float4*)(cA + pos1);
    const float4 w11 = *(const float4*)(cA + pos1 + 4);
    const float4 w20 = *(const float4*)(cB + pos2);
    const float4 w21 = *(const float4*)(cB + pos2 + 4);
    const float4 w30 = *(const float4*)(cB + pos3);
    const float4 w31 = *(const float4*)(cB + pos3 + 4);
    // marker: all 8 float4s simultaneously live -> scheduler has no reg-pressure
    // reason to serialize; single lgkmcnt wait lands here.
    asm volatile("" :: "v"(w00.x), "v"(w01.x), "v"(w10.x), "v"(w11.x),
                       "v"(w20.x), "v"(w21.x), "v"(w30.x), "v"(w31.x));

    // ---- phase 3: all cnts -> lower/upper (pure VALU) ----
    // lower = largest i with cdf[i] < uv (0 if none); cdf[63]=1 exact keeps
    // lower<=62 for uv<1. uv<=0 -> upper=0 -> chi=cdf[0]=0 falls out free.
    #define CNT(w0_, w1_, uv_) ((int)(w0_.y < uv_) + (int)(w0_.z < uv_) + \
        (int)(w0_.w < uv_) + (int)(w1_.x < uv_) + (int)(w1_.y < uv_) + \
        (int)(w1_.z < uv_) + (int)(w1_.w < uv_))
    const int lo0 = pos0 + CNT(w00, w01, uv0);
    const int lo1 = pos1 + CNT(w10, w11, uv1);
    const int lo2 = pos2 + CNT(w20, w21, uv2);
    const int lo3 = pos3 + CNT(w30, w31, uv3);
    #undef CNT
    const int up0 = (uv0 > 0.0f) ? (lo0 + 1) : 0;
    const int up1 = (uv1 > 0.0f) ? (lo1 + 1) : 0;
    const int up2 = (uv2 > 0.0f) ? (lo2 + 1) : 0;
    const int up3 = (uv3 > 0.0f) ? (lo3 + 1) : 0;

    // ---- phase 4: ALL 16 crossbar gathers, ONE lgkm round ----
    const float l0 = bperm_f(cdfvA, lo0), h0 = bperm_f(cdfvA, up0);
    const float p0 = bperm_f(bvA,  lo0), q0 = bperm_f(bvA,  up0);
    const float l1 = bperm_f(cdfvA, lo1), h1 = bperm_f(cdfvA, up1);
    const float p1 = bperm_f(bvA,  lo1), q1 = bperm_f(bvA,  up1);
    const float l2 = bperm_f(cdfvB, lo2), h2 = bperm_f(cdfvB, up2);
    const float p2 = bperm_f(bvB,  lo2), q2 = bperm_f(bvB,  up2);
    const float l3 = bperm_f(cdfvB, lo3), h3 = bperm_f(cdfvB, up3);
    const float p3 = bperm_f(bvB,  lo3), q3 = bperm_f(bvB,  up3);
    asm volatile("" :: "v"(l0), "v"(h0), "v"(p0), "v"(q0),
                       "v"(l1), "v"(h1), "v"(p1), "v"(q1),
                       "v"(l2), "v"(h2), "v"(p2), "v"(q2),
                       "v"(l3), "v"(h3), "v"(p3), "v"(q3));

    // ---- phase 5: finals ----
    #define FINAL(uv_, l_, h_, p_, q_, dst_) { \
        float den = h_ - l_; \
        den = (den < 1e-5f) ? 1.0f : den; \
        const float t = (uv_ - l_) * __builtin_amdgcn_rcpf(den); \
        dst_ = __builtin_fmaf(t, q_ - p_, p_); }
    float2 resA, resB;
    FINAL(uv0, l0, h0, p0, q0, resA.x);
    FINAL(uv1, l1, h1, p1, q1, resA.y);
    FINAL(uv2, l2, h2, p2, q2, resB.x);
    FINAL(uv3, l3, h3, p3, q3, resB.y);
    #undef FINAL

    ((float2*)out)[rA * (NIMP / 2) + lane] = resA;
    ((float2*)out)[rB * (NIMP / 2) + lane] = resB;
}

extern "C" void kernel_launch(void* const* d_in, const int* in_sizes, int n_in,
                              void* d_out, int out_size, void* d_ws, size_t ws_size,
                              hipStream_t stream) {
    const float* bins    = (const float*)d_in[0];
    const float* weights = (const float*)d_in[1];
    const float* u       = (const float*)d_in[2];
    float* out = (float*)d_out;

    const int n_rays = in_sizes[0] / NBINS;
    const int grid = (n_rays + RAYS_PER_BLOCK - 1) / RAYS_PER_BLOCK;
    sample_pdf_kernel<<<grid, 1024, 0, stream>>>(bins, weights, u, out, n_rays);
}